// Round 1
// baseline (83.947 us; speedup 1.0000x reference)
//
#include <hip/hip_runtime.h>

#define N_EVAL 2001
#define NCTRL  64
// degree p = 3 fixed by the problem; knots: [0,0,0,0, 1/61..60/61, 1,1,1,1] (len 68)

__device__ __forceinline__ float knotv(int i) {
    if (i <= 3) return 0.0f;
    if (i >= NCTRL) return 1.0f;           // indices 64..67 are the clamped 1.0s
    return (float)(i - 3) * (1.0f / 61.0f); // matches linspace(0,1,62) internals
}

// Cox-de-Boor, degree 3 (NURBS book A2.1/A2.2), searchsorted(side='right') span
__device__ __forceinline__ void basis_p3(float u, int& span, float4& N) {
    int s = 3 + (int)floorf(u * 61.0f);
    s = max(3, min(63, s));
    // correct against actual knot comparisons (fp safety, exact searchsorted semantics)
    while (s < 63 && knotv(s + 1) <= u) ++s;
    while (s > 3 && knotv(s) > u) --s;

    float left[4], right[4], Ns[4];
    Ns[0] = 1.0f;
    #pragma unroll
    for (int j = 1; j <= 3; ++j) {
        left[j]  = u - knotv(s + 1 - j);
        right[j] = knotv(s + j) - u;
        float saved = 0.0f;
        #pragma unroll
        for (int r = 0; r < j; ++r) {
            float temp = Ns[r] / (right[r + 1] + left[j - r]);
            Ns[r] = saved + right[r + 1] * temp;
            saved = left[j - r] * temp;
        }
        Ns[j] = saved;
    }
    span = s;
    N = make_float4(Ns[0], Ns[1], Ns[2], Ns[3]);
}

__global__ void basis_kernel(const float* __restrict__ pu, const float* __restrict__ pv,
                             float4* __restrict__ Bu, float4* __restrict__ Bv,
                             int* __restrict__ su, int* __restrict__ sv) {
    int gid = blockIdx.x * blockDim.x + threadIdx.x;
    if (gid < 2048) {
        if (gid < N_EVAL) {
            int s; float4 N;
            basis_p3(pu[gid], s, N);
            Bu[gid] = N; su[gid] = s;
        }
    } else {
        int i = gid - 2048;
        if (i < N_EVAL) {
            int s; float4 N;
            basis_p3(pv[i], s, N);
            Bv[i] = N; sv[i] = s;
        }
    }
}

// One block per (u, 256 consecutive v). Stage 1: u-contracted curve row -> LDS.
// Stage 2: per-thread v-contraction, contiguous 12B store per point.
__global__ __launch_bounds__(256) void eval_kernel(const float* __restrict__ cp,
                                                   const float4* __restrict__ Bu,
                                                   const float4* __restrict__ Bv,
                                                   const int* __restrict__ su,
                                                   const int* __restrict__ sv,
                                                   float* __restrict__ out) {
    __shared__ float4 lds4[NCTRL];              // curve row: (x,y,z,pad) per j
    const int u = blockIdx.y;
    const int t = threadIdx.x;
    const int s_u = su[u];                      // wave-uniform -> scalar load
    const float4 bu = Bu[u];

    // stage 1: 192 threads, each computes one (j,d). CP rows are 192 contiguous
    // floats, so loads are perfectly coalesced; CP (48KB) stays L1/L2 resident.
    if (t < NCTRL * 3) {
        const int base = (s_u - 3) * (NCTRL * 3);
        float c = bu.x * cp[base +       t]
                + bu.y * cp[base + 192 + t]
                + bu.z * cp[base + 384 + t]
                + bu.w * cp[base + 576 + t];
        int j = t / 3, d = t - 3 * j;
        ((float*)lds4)[j * 4 + d] = c;
    }
    __syncthreads();

    const int v = blockIdx.x * 256 + t;
    if (v >= N_EVAL) return;
    const float4 bv = Bv[v];
    const int iv0 = sv[v] - 3;                  // in [0,60]
    float4 c0 = lds4[iv0 + 0];
    float4 c1 = lds4[iv0 + 1];
    float4 c2 = lds4[iv0 + 2];
    float4 c3 = lds4[iv0 + 3];
    float x = bv.x * c0.x + bv.y * c1.x + bv.z * c2.x + bv.w * c3.x;
    float y = bv.x * c0.y + bv.y * c1.y + bv.z * c2.y + bv.w * c3.y;
    float z = bv.x * c0.z + bv.y * c1.z + bv.z * c2.z + bv.w * c3.z;

    size_t o = ((size_t)u * N_EVAL + v) * 3;
    out[o + 0] = x;
    out[o + 1] = y;
    out[o + 2] = z;
}

extern "C" void kernel_launch(void* const* d_in, const int* in_sizes, int n_in,
                              void* d_out, int out_size, void* d_ws, size_t ws_size,
                              hipStream_t stream) {
    const float* cp = (const float*)d_in[0];   // [64,64,3] f32
    const float* pu = (const float*)d_in[1];   // [2001] f32
    const float* pv = (const float*)d_in[2];   // [2001] f32
    float* out = (float*)d_out;                // [2001,2001,3] f32

    // ws layout: Bu f4[2048] | Bv f4[2048] | su i32[2048] | sv i32[2048] = 80KB
    float4* Bu = (float4*)d_ws;
    float4* Bv = Bu + 2048;
    int* su = (int*)(Bu + 4096);
    int* sv = su + 2048;

    basis_kernel<<<16, 256, 0, stream>>>(pu, pv, Bu, Bv, su, sv);

    dim3 grid((N_EVAL + 255) / 256, N_EVAL);
    eval_kernel<<<grid, 256, 0, stream>>>(cp, Bu, Bv, su, sv, out);
}

// Round 2
// 83.052 us; speedup vs baseline: 1.0108x; 1.0108x over previous
//
#include <hip/hip_runtime.h>

#define N_EVAL 2001
#define NCTRL  64
// degree p = 3; clamped knots: [0,0,0,0, 1/61..60/61, 1,1,1,1] (len 68)

__device__ __forceinline__ float knotv(int i) {
    if (i <= 3) return 0.0f;
    if (i >= NCTRL) return 1.0f;
    return (float)(i - 3) * (1.0f / 61.0f);
}

// Cox-de-Boor degree 3, searchsorted(side='right') span semantics
__device__ __forceinline__ void basis_p3(float u, int& span, float4& N) {
    int s = 3 + (int)floorf(u * 61.0f);
    s = max(3, min(63, s));
    while (s < 63 && knotv(s + 1) <= u) ++s;
    while (s > 3 && knotv(s) > u) --s;

    float left[4], right[4], Ns[4];
    Ns[0] = 1.0f;
    #pragma unroll
    for (int j = 1; j <= 3; ++j) {
        left[j]  = u - knotv(s + 1 - j);
        right[j] = knotv(s + j) - u;
        float saved = 0.0f;
        #pragma unroll
        for (int r = 0; r < j; ++r) {
            float temp = Ns[r] / (right[r + 1] + left[j - r]);
            Ns[r] = saved + right[r + 1] * temp;
            saved = left[j - r] * temp;
        }
        Ns[j] = saved;
    }
    span = s;
    N = make_float4(Ns[0], Ns[1], Ns[2], Ns[3]);
}

__global__ void basis_kernel(const float* __restrict__ pu, const float* __restrict__ pv,
                             float4* __restrict__ Bu, float4* __restrict__ Bv,
                             int* __restrict__ su, int* __restrict__ sv) {
    int gid = blockIdx.x * blockDim.x + threadIdx.x;
    if (gid < 2048) {
        if (gid < N_EVAL) {
            int s; float4 N;
            basis_p3(pu[gid], s, N);
            Bu[gid] = N; su[gid] = s;
        }
    } else {
        int i = gid - 2048;
        if (i < N_EVAL) {
            int s; float4 N;
            basis_p3(pv[i], s, N);
            Bv[i] = N; sv[i] = s;
        }
    }
}

// One block per u-row. Stage 1 once per row; 8 v-points per thread;
// stores staged through LDS so every store instr is 256B contiguous.
__global__ __launch_bounds__(256) void eval_kernel(const float* __restrict__ cp,
                                                   const float4* __restrict__ Bu,
                                                   const float4* __restrict__ Bv,
                                                   const int* __restrict__ su,
                                                   const int* __restrict__ sv,
                                                   float* __restrict__ out) {
    __shared__ float4 curve[NCTRL];    // u-contracted row: (x,y,z,pad) per j
    __shared__ float  stage[768];      // 256 points * 3 floats store staging

    const int u = blockIdx.x;
    const int t = threadIdx.x;
    const int s_u = su[u];             // uniform -> broadcast
    const float4 bu = Bu[u];

    // stage 1: 192 threads, one (j,d) each; CP rows = 192 contiguous floats
    if (t < NCTRL * 3) {
        const int base = (s_u - 3) * (NCTRL * 3);
        float c = bu.x * cp[base +       t]
                + bu.y * cp[base + 192 + t]
                + bu.z * cp[base + 384 + t]
                + bu.w * cp[base + 576 + t];
        int j = t / 3, d = t - 3 * j;
        ((float*)curve)[j * 4 + d] = c;
    }
    __syncthreads();

    float* orow = out + (size_t)u * (N_EVAL * 3);

    #pragma unroll
    for (int k = 0; k < 8; ++k) {
        const int v = k * 256 + t;
        float x = 0.f, y = 0.f, z = 0.f;
        if (v < N_EVAL) {
            const float4 bv = Bv[v];
            const int iv0 = sv[v] - 3;          // in [0,60]
            float4 c0 = curve[iv0 + 0];
            float4 c1 = curve[iv0 + 1];
            float4 c2 = curve[iv0 + 2];
            float4 c3 = curve[iv0 + 3];
            x = bv.x * c0.x + bv.y * c1.x + bv.z * c2.x + bv.w * c3.x;
            y = bv.x * c0.y + bv.y * c1.y + bv.z * c2.y + bv.w * c3.y;
            z = bv.x * c0.z + bv.y * c1.z + bv.z * c2.z + bv.w * c3.z;
        }
        if (k) __syncthreads();                 // WAR on stage from prev iter
        if (v < N_EVAL) {
            stage[3 * t + 0] = x;               // stride-3 dwords: 2-way bank alias, free
            stage[3 * t + 1] = y;
            stage[3 * t + 2] = z;
        }
        __syncthreads();
        const int rowbase = k * 768;
        #pragma unroll
        for (int j = 0; j < 3; ++j) {
            int idx = j * 256 + t;              // contiguous 256B per wave-instr
            if (rowbase + idx < N_EVAL * 3)
                orow[rowbase + idx] = stage[idx];
        }
    }
}

extern "C" void kernel_launch(void* const* d_in, const int* in_sizes, int n_in,
                              void* d_out, int out_size, void* d_ws, size_t ws_size,
                              hipStream_t stream) {
    const float* cp = (const float*)d_in[0];   // [64,64,3] f32
    const float* pu = (const float*)d_in[1];   // [2001] f32
    const float* pv = (const float*)d_in[2];   // [2001] f32
    float* out = (float*)d_out;                // [2001,2001,3] f32

    // ws: Bu f4[2048] | Bv f4[2048] | su i32[2048] | sv i32[2048] = 80KB
    float4* Bu = (float4*)d_ws;
    float4* Bv = Bu + 2048;
    int* su = (int*)(Bu + 4096);
    int* sv = su + 2048;

    basis_kernel<<<16, 256, 0, stream>>>(pu, pv, Bu, Bv, su, sv);
    eval_kernel<<<N_EVAL, 256, 0, stream>>>(cp, Bu, Bv, su, sv, out);
}